// Round 4
// baseline (239.853 us; speedup 1.0000x reference)
//
#include <hip/hip_runtime.h>

// FWHT over last dim (4096) of [8192, 4096] fp32, normalized by 1/64.
// Persistent-ish pipelined version: 2048 single-wave blocks, 4 consecutive
// rows per block, double-buffered LDS staging with COUNTED vmcnt waits.
//
// Per row (radix-64 x 64, identical math/swizzle to the verified kernel):
//   stage:  16 x global_load_lds, 1024 B wave-contiguous each; the GLOBAL
//           source address is pre-swizzled so the (linear-write) LDS image
//           carries the XOR chunk swizzle: chunk (hi,c) -> slot hi*16+(c^(hi&15)).
//   pass 1: lane l reads its row hi=l via 16 x ds_read_b128 (conflict-free),
//           fwht64 over bits 0..5 in registers.
//   transp: write back into the SAME chunk slots (lane-local overwrite).
//   pass 2: column read ds_read_b32 (exact 2 lanes/bank = free), fwht64 over
//           bits 6..11, scale, coalesced dword stores (256 B/instr).
//
// Pipeline: while computing row r from buf[cur], loads for row r+1 are in
// flight into buf[cur^1]. The wait for buf[cur] is s_waitcnt vmcnt(63):
// vmem ops retire IN ORDER, and exactly 64 stores (row r-1) are younger than
// buf[cur]'s 16 loads, so outstanding<=63 guarantees those loads completed --
// without draining the stores or the next prefetch. No vmcnt(0) in steady
// state, no __syncthreads anywhere (single wave per block).

#define N        4096
#define THREADS  64
#define RPB      4            // rows per block -> 64 KiB contiguous per stream
#define BUF_FLOATS 4096       // 16 KiB per buffer, x2 = 32 KiB -> 5 blocks/CU

__device__ __forceinline__ void fwht64(float v[64]) {
    // In-place 64-point FWHT, stages LSB->MSB (stride 1,2,4,8,16,32) --
    // same summation tree as the reference recursion.
#pragma unroll
    for (int s = 1; s < 64; s <<= 1) {
#pragma unroll
        for (int k = 0; k < 64; k++) {
            if ((k & s) == 0) {
                float a = v[k];
                float b = v[k + s];
                v[k]     = a + b;
                v[k + s] = a - b;
            }
        }
    }
}

__global__ __launch_bounds__(THREADS)
void FWHT_83476984365427_kernel(const float* __restrict__ x,
                                float* __restrict__ out,
                                int nrows) {
    __shared__ float lds[2][BUF_FLOATS];

    const int r0 = blockIdx.x * RPB;
    if (r0 >= nrows) return;

    const int l  = threadIdx.x;   // lane 0..63
    const int lh = l >> 4;        // 0..3
    const int ls = l & 15;        // 0..15

    // Stage one row into lds[buf]: LDS write is linear (slot 64*i + lane);
    // slot s holds global chunk (hi = s>>4, c = (s&15) ^ (hi&15)).
    auto STAGE = [&](int row, int buf) {
        const float* __restrict__ xr = x + (size_t)row * N;
#pragma unroll
        for (int i = 0; i < 16; i++) {
            const int hi = 4 * i + lh;
            const int hm = 4 * (i & 3) + lh;      // == hi & 15 (no carry)
            const int c  = ls ^ hm;
            const float* src = xr + hi * 64 + c * 4;
            __builtin_amdgcn_global_load_lds(
                (const __attribute__((address_space(1))) void*)src,
                (__attribute__((address_space(3))) void*)(&lds[buf][i * 256]),
                16, 0, 0);
        }
    };

    // Prologue: start the first row's loads.
    STAGE(r0, 0);

    for (int j = 0; j < RPB; j++) {
        const int row = r0 + j;
        if (row >= nrows) break;
        const int cur = j & 1;

        // Wait for buf[cur]'s 16 loads. j==0: nothing else outstanding ->
        // vmcnt(0). j>0: exactly 64 stores (row j-1) are younger than these
        // loads; in-order retirement makes vmcnt(63) sufficient and minimal.
        if (j == 0) asm volatile("s_waitcnt vmcnt(0)" ::: "memory");
        else        asm volatile("s_waitcnt vmcnt(63)" ::: "memory");

        // Prefetch next row into the other buffer (overlaps this row's compute).
        if (j + 1 < RPB && row + 1 < nrows) STAGE(row + 1, cur ^ 1);

        float v[64];
        const float* __restrict__ bp = &lds[cur][0];

        // ---- Row read: chunk (hi=l, c) lives at bp[l*64 + 4*(c ^ (l&15))].
        {
            const float* rowp = bp + l * 64;
#pragma unroll
            for (int c = 0; c < 16; c++) {
                float4 f = *(const float4*)(rowp + ((c ^ ls) << 2));
                v[4 * c + 0] = f.x;
                v[4 * c + 1] = f.y;
                v[4 * c + 2] = f.z;
                v[4 * c + 3] = f.w;
            }
        }

        // ---- FWHT over element bits 0..5.
        fwht64(v);

        // ---- Transpose write: same chunk slots (lane-local overwrite).
        {
            float* rowp = (float*)bp + l * 64;
#pragma unroll
            for (int c = 0; c < 16; c++) {
                float4 f;
                f.x = v[4 * c + 0];
                f.y = v[4 * c + 1];
                f.z = v[4 * c + 2];
                f.w = v[4 * c + 3];
                *(float4*)(rowp + ((c ^ ls) << 2)) = f;
            }
        }
        // Order transpose writes before column reads (single wave: counter only).
        asm volatile("s_waitcnt lgkmcnt(0)" ::: "memory");

        // ---- Column read: element (m, lane l) at
        // bp[m*64 + 4*((l>>2) ^ (m&15)) + (l&3)] -> exactly 2 lanes/bank.
        {
            const int l2 = l >> 2;
            const int jj = l & 3;
#pragma unroll
            for (int ml = 0; ml < 16; ml++) {
                const int off = ((l2 ^ ml) << 2) + jj;
#pragma unroll
                for (int mh = 0; mh < 4; mh++) {
                    v[mh * 16 + ml] = bp[(mh * 16 + ml) * 64 + off];
                }
            }
        }

        // ---- FWHT over element bits 6..11.
        fwht64(v);

        // ---- Scale (exact 2^-6) and store: 256 B wave-contiguous per instr.
        {
            float* __restrict__ otr = out + (size_t)row * N;
            const float scale = 1.0f / 64.0f;
#pragma unroll
            for (int m = 0; m < 64; m++) otr[m * 64 + l] = v[m] * scale;
        }
    }
}

extern "C" void kernel_launch(void* const* d_in, const int* in_sizes, int n_in,
                              void* d_out, int out_size, void* d_ws, size_t ws_size,
                              hipStream_t stream) {
    (void)n_in; (void)d_ws; (void)ws_size; (void)out_size;
    const float* x = (const float*)d_in[0];
    float* out = (float*)d_out;
    const int nrows = in_sizes[0] / N;
    dim3 grid((nrows + RPB - 1) / RPB);
    dim3 block(THREADS);
    FWHT_83476984365427_kernel<<<grid, block, 0, stream>>>(x, out, nrows);
}

// Round 5
// 234.250 us; speedup vs baseline: 1.0239x; 1.0239x over previous
//
#include <hip/hip_runtime.h>

// FWHT over last dim (4096) of [8192, 4096] fp32, normalized by 1/64.
// PURE-STREAM structure (the only structure measured at ~6.3 TB/s on this
// chip): no LDS allocation, no barriers, register-resident row, cross-lane
// butterflies via shuffles. One wave per row, 4 independent waves per block.
//
// Layout: load instr i gives lane l the float4 at row offset i*256 + 4l,
// i.e. element e = i*256 + 4l + j  ->  e[1:0]=j (in-reg), e[7:2]=lane,
// e[11:8]=i (across regs). Stages strictly LSB->MSB (same summation tree as
// the reference recursion -> bit-exact):
//   e-bit 0,1   : in-register pairs (r, r^1), (r, r^2)
//   e-bit 2..7  : cross-lane, __shfl_xor masks 1,2,4,8,16,32;
//                 butterfly = fmaf(sgn, own, partner), sgn = lane-uniform
//                 +/-1  ->  lo lane: own+p = a+b, hi lane: p-own = a-b
//                 (fma with +/-1.0 is exact, single rounding, == a+b / a-b)
//   e-bit 8..11 : in-register pairs (r, r^4), (r, r^8), (r, r^16), (r, r^32)
// Loads AND stores are 16 x dwordx4, each 1 KB wave-contiguous. With no
// LDS-wait-all in the path the compiler emits progressive vmcnt(N) waits:
// the first butterflies start as soon as the first chunks arrive.

#define N        4096
#define THREADS  256    // 4 independent waves per block (no barriers)

__global__ __launch_bounds__(THREADS)
void FWHT_83476984365427_kernel(const float* __restrict__ x,
                                float* __restrict__ out,
                                int nrows) {
    const int wid = blockIdx.x * (THREADS / 64) + (threadIdx.x >> 6);
    if (wid >= nrows) return;
    const int l = threadIdx.x & 63;

    const float* __restrict__ xr  = x   + (size_t)wid * N;
    float* __restrict__       otr = out + (size_t)wid * N;

    float v[64];

    // ---- Load: 16 x dwordx4, instr i = 1 KB wave-contiguous.
#pragma unroll
    for (int i = 0; i < 16; i++) {
        float4 f = *(const float4*)(xr + i * 256 + l * 4);
        v[4 * i + 0] = f.x;
        v[4 * i + 1] = f.y;
        v[4 * i + 2] = f.z;
        v[4 * i + 3] = f.w;
    }

    // ---- Element bits 0..1: in-register (within each float4).
#pragma unroll
    for (int s = 1; s < 4; s <<= 1) {
#pragma unroll
        for (int k = 0; k < 64; k++) {
            if ((k & s) == 0) {
                float a = v[k];
                float b = v[k + s];
                v[k]     = a + b;
                v[k + s] = a - b;
            }
        }
    }

    // ---- Element bits 2..7: cross-lane butterflies, masks 1..32 (LSB->MSB).
#pragma unroll
    for (int m = 1; m < 64; m <<= 1) {
        const float sgn = (l & m) ? -1.0f : 1.0f;
#pragma unroll
        for (int r = 0; r < 64; r++) {
            float p = __shfl_xor(v[r], m, 64);
            v[r] = fmaf(sgn, v[r], p);   // lo: own+p = a+b ; hi: p-own = a-b
        }
    }

    // ---- Element bits 8..11: in-register (across the 16 float4 chunks).
#pragma unroll
    for (int s = 4; s < 64; s <<= 1) {
#pragma unroll
        for (int k = 0; k < 64; k++) {
            if ((k & s) == 0) {
                float a = v[k];
                float b = v[k + s];
                v[k]     = a + b;
                v[k + s] = a - b;
            }
        }
    }

    // ---- Scale (exact 2^-6) and store: 16 x dwordx4, 1 KB contiguous each.
    const float scale = 1.0f / 64.0f;
#pragma unroll
    for (int i = 0; i < 16; i++) {
        float4 f;
        f.x = v[4 * i + 0] * scale;
        f.y = v[4 * i + 1] * scale;
        f.z = v[4 * i + 2] * scale;
        f.w = v[4 * i + 3] * scale;
        *(float4*)(otr + i * 256 + l * 4) = f;
    }
}

extern "C" void kernel_launch(void* const* d_in, const int* in_sizes, int n_in,
                              void* d_out, int out_size, void* d_ws, size_t ws_size,
                              hipStream_t stream) {
    (void)n_in; (void)d_ws; (void)ws_size; (void)out_size;
    const float* x = (const float*)d_in[0];
    float* out = (float*)d_out;
    const int nrows = in_sizes[0] / N;
    const int wpb = THREADS / 64;
    dim3 grid((nrows + wpb - 1) / wpb);
    dim3 block(THREADS);
    FWHT_83476984365427_kernel<<<grid, block, 0, stream>>>(x, out, nrows);
}